// Round 7
// baseline (503.025 us; speedup 1.0000x reference)
//
#include <hip/hip_runtime.h>

// SAdapter v7: split streaming kernels, occupancy-tuned (v6 lesson: (256,4)
// capped both kernels at 4 blocks/CU; k1 needs waves to hide strided-read
// latency, k3 to hide the write stream).
// K1: t = tok @ W1^T + b1   (reads x 310MB, writes t 12.9MB, no barriers, (256,8))
// K3: t -> z_star -> P -> z_hist -> y  (reads t, writes out 310MB, (256,6))

#define DIMD 192

// ---------------- K1: token projection ----------------
__launch_bounds__(256, 8)
__global__ void k1_tproj(const float* __restrict__ x,
                         const float* __restrict__ W1,
                         const float* __restrict__ b1,
                         float* __restrict__ tbuf)
{
    const int tg = blockIdx.x * 256 + threadIdx.x;   // 0..401407 = 2048*196
    const int b  = tg / 196;
    const int n  = tg - b * 196;
    const float4* rowp = (const float4*)(x + (size_t)b * (197 * DIMD) + DIMD + (size_t)n * DIMD);

    float acc[8];
    #pragma unroll
    for (int c = 0; c < 8; ++c) acc[c] = b1[c];            // uniform -> s_load
    #pragma unroll
    for (int blk = 0; blk < 12; ++blk) {                   // 12 batches of 16 d
        float4 tv[4];
        #pragma unroll
        for (int u = 0; u < 4; ++u) tv[u] = rowp[blk * 4 + u];
        #pragma unroll
        for (int c = 0; c < 8; ++c) {
            const float* wrow = W1 + c * DIMD + blk * 16;  // 16 contiguous, uniform
            #pragma unroll
            for (int u = 0; u < 4; ++u) {
                acc[c] += tv[u].x * wrow[u * 4 + 0] + tv[u].y * wrow[u * 4 + 1]
                        + tv[u].z * wrow[u * 4 + 2] + tv[u].w * wrow[u * 4 + 3];
            }
        }
    }
    float4* op = (float4*)(tbuf + (size_t)tg * 8);         // 32B/lane
    op[0] = make_float4(acc[0], acc[1], acc[2], acc[3]);
    op[1] = make_float4(acc[4], acc[5], acc[6], acc[7]);
}

// ---------------- K3: per-image tail (BC -> C2 -> D) ----------------
__launch_bounds__(256, 6)
__global__ void k3_tail(const float* __restrict__ x,
                        const float* __restrict__ tbuf,
                        const float* __restrict__ conv1_w,
                        const float* __restrict__ conv1_b,
                        const float* __restrict__ cdc_w,
                        const float* __restrict__ wc1,
                        const float* __restrict__ wc2,
                        const float* __restrict__ hist_w,
                        const float* __restrict__ hist_b,
                        float* __restrict__ out)
{
    __shared__ float smem[4608];   // 18432 B
    float* TS  = smem;             // [8][16][16] padded t (border 0); dead after BC
    float* ZH  = smem;             // [1568] flat z_hist (c*196+hw), overlays TS
    float* PS  = smem + 2048;      // [8][16][16] padded P (border 1)
    float* WB2 = smem + 4096;      // [64][8] packed small weights

    const int tid = threadIdx.x;
    const float* xb   = x   + (size_t)blockIdx.x * (197 * DIMD);
    float*       outb = out + (size_t)blockIdx.x * (197 * DIMD);

    // ---- Phase 0: init borders, pack weights, class-token copy ----
    {
        float4 z4 = make_float4(0.f, 0.f, 0.f, 0.f);
        float4 o4 = make_float4(1.f, 1.f, 1.f, 1.f);
        ((float4*)TS)[tid]       = z4;
        ((float4*)TS)[tid + 256] = z4;
        ((float4*)PS)[tid]       = o4;
        ((float4*)PS)[tid + 256] = o4;
    }
    if (tid < 64) {
        const float* c5 = cdc_w + tid * 5;                 // cdc_w (8,8,1,5), tid=o*8+i
        float k0 = c5[0], k1 = c5[1], k2 = c5[2], k3 = c5[3], k4 = c5[4];
        float kd = k0 + k1 + k2 + k3 + k4;
        float* wp = WB2 + tid * 8;
        wp[0] = conv1_w[tid] + k2 - 0.7f * kd;  // center: 1x1 + cdc-center - theta*diff
        wp[1] = k0; wp[2] = k1; wp[3] = k3; wp[4] = k4;    // up,left,right,down
        wp[5] = wc1[tid];
        wp[6] = wc2[tid];
        wp[7] = 0.f;
    } else if (tid >= 208) {
        ((float4*)outb)[tid - 208] = ((const float4*)xb)[tid - 208];  // class token
    }
    __syncthreads();

    // ---- Phase T: load t-slice (32B/lane), scatter into padded TS ----
    if (tid < 196) {
        const float4* tp4 = (const float4*)(tbuf + ((size_t)blockIdx.x * 196 + tid) * 8);
        float4 v0 = tp4[0], v1 = tp4[1];
        int h = tid / 14, w = tid - h * 14;
        float* tp = TS + (h + 1) * 16 + (w + 1);
        tp[0*256] = v0.x; tp[1*256] = v0.y; tp[2*256] = v0.z; tp[3*256] = v0.w;
        tp[4*256] = v1.x; tp[5*256] = v1.y; tp[6*256] = v1.z; tp[7*256] = v1.w;
    }
    __syncthreads();

    // ---- Phase BC: z_star in regs -> mu/gamma -> P = exp(-(g*(z-mu))^2) ----
    if (tid < 196) {
        int h = tid / 14, w = tid - h * 14;
        const float* tp = TS + (h + 1) * 16 + (w + 1);
        float zv[8];
        #pragma unroll
        for (int c = 0; c < 8; ++c) zv[c] = conv1_b[c];    // uniform -> s_load
        #pragma unroll
        for (int i = 0; i < 8; ++i) {
            float t0 = tp[i * 256];
            float tu = tp[i * 256 - 16];
            float td = tp[i * 256 + 16];
            float tl = tp[i * 256 - 1];
            float tr = tp[i * 256 + 1];
            #pragma unroll
            for (int c = 0; c < 8; ++c) {
                const float* wp = WB2 + (c * 8 + i) * 8;   // broadcast b128 + b32
                float4 wv = *(const float4*)wp;
                float wd = wp[4];
                zv[c] += wv.x * t0 + wv.y * tu + wv.z * tl + wv.w * tr + wd * td;
            }
        }
        float* pp = PS + (h + 1) * 16 + (w + 1);
        #pragma unroll
        for (int c = 0; c < 8; ++c) {
            float mu = 0.f, ga = 0.f;
            #pragma unroll
            for (int i = 0; i < 8; ++i) {
                const float* wp = WB2 + (c * 8 + i) * 8;
                mu += wp[5] * zv[i];
                ga += wp[6] * zv[i];
            }
            float e = ga * (zv[c] - mu);
            pp[c * 256] = __expf(-e * e);
        }
    }
    __syncthreads();

    // ---- Phase C2: z_hist = 3x3 box sum / 9, flat (c*196+hw) into ZH (over TS) ----
    if (tid < 196) {
        int h = tid / 14, w = tid - h * 14;
        const float* pb = PS + h * 16 + w;    // top-left of 3x3 window (padded coords)
        #pragma unroll
        for (int c = 0; c < 8; ++c) {
            const float* pr = pb + c * 256;
            float s9 = pr[0]  + pr[1]  + pr[2]
                     + pr[16] + pr[17] + pr[18]
                     + pr[32] + pr[33] + pr[34];
            ZH[c * 196 + tid] = s9 * (1.f / 9.f);
        }
    }
    __syncthreads();

    // ---- Phase D: y rows; hist_w in regs, ZH broadcast reads, coalesced stores ----
    if (tid < 192) {
        const int d4 = tid % 48;
        const int g  = tid / 48;
        float hwf[32];
        {
            const float4* hwp = (const float4*)(hist_w + d4 * 32);  // contiguous 128B
            #pragma unroll
            for (int u = 0; u < 8; ++u) {
                float4 v = hwp[u];
                hwf[u * 4 + 0] = v.x; hwf[u * 4 + 1] = v.y;
                hwf[u * 4 + 2] = v.z; hwf[u * 4 + 3] = v.w;
            }
        }
        const float4 hb = *(const float4*)(hist_b + d4 * 4);
        float4* outy = (float4*)(outb + DIMD);
        for (int n2 = g; n2 < 196; n2 += 4) {
            const float4 z0 = *(const float4*)(ZH + n2 * 8);      // broadcast b128
            const float4 z1 = *(const float4*)(ZH + n2 * 8 + 4);  // broadcast b128
            float4 a = hb;
            a.x += z0.x*hwf[0]  + z0.y*hwf[1]  + z0.z*hwf[2]  + z0.w*hwf[3]
                 + z1.x*hwf[4]  + z1.y*hwf[5]  + z1.z*hwf[6]  + z1.w*hwf[7];
            a.y += z0.x*hwf[8]  + z0.y*hwf[9]  + z0.z*hwf[10] + z0.w*hwf[11]
                 + z1.x*hwf[12] + z1.y*hwf[13] + z1.z*hwf[14] + z1.w*hwf[15];
            a.z += z0.x*hwf[16] + z0.y*hwf[17] + z0.z*hwf[18] + z0.w*hwf[19]
                 + z1.x*hwf[20] + z1.y*hwf[21] + z1.z*hwf[22] + z1.w*hwf[23];
            a.w += z0.x*hwf[24] + z0.y*hwf[25] + z0.z*hwf[26] + z0.w*hwf[27]
                 + z1.x*hwf[28] + z1.y*hwf[29] + z1.z*hwf[30] + z1.w*hwf[31];
            outy[n2 * 48 + d4] = a;   // lanes: contiguous float4 -> coalesced
        }
    }
}

// ---------------- fused fallback (only if ws too small) ----------------
__launch_bounds__(256, 4)
__global__ void sadapter_fused(const float* __restrict__ x,
    const float* __restrict__ W1, const float* __restrict__ b1,
    const float* __restrict__ conv1_w, const float* __restrict__ conv1_b,
    const float* __restrict__ cdc_w, const float* __restrict__ wc1,
    const float* __restrict__ wc2, const float* __restrict__ hist_w,
    const float* __restrict__ hist_b, float* __restrict__ out)
{
    __shared__ float smem[4608];
    float* TS  = smem;
    float* ZH  = smem;
    float* PS  = smem + 2048;
    float* WB2 = smem + 4096;
    const int tid = threadIdx.x;
    const float* xb   = x   + (size_t)blockIdx.x * (197 * DIMD);
    float*       outb = out + (size_t)blockIdx.x * (197 * DIMD);

    {
        float4 z4 = make_float4(0.f,0.f,0.f,0.f), o4 = make_float4(1.f,1.f,1.f,1.f);
        ((float4*)TS)[tid] = z4; ((float4*)TS)[tid+256] = z4;
        ((float4*)PS)[tid] = o4; ((float4*)PS)[tid+256] = o4;
    }
    if (tid < 64) {
        const float* c5 = cdc_w + tid * 5;
        float k0=c5[0],k1=c5[1],k2=c5[2],k3=c5[3],k4=c5[4];
        float kd = k0+k1+k2+k3+k4;
        float* wp = WB2 + tid*8;
        wp[0]=conv1_w[tid]+k2-0.7f*kd; wp[1]=k0; wp[2]=k1; wp[3]=k3; wp[4]=k4;
        wp[5]=wc1[tid]; wp[6]=wc2[tid]; wp[7]=0.f;
    }
    __syncthreads();
    if (tid < 196) {
        const float4* rowp = (const float4*)(xb + DIMD + tid * DIMD);
        float acc[8];
        #pragma unroll
        for (int c=0;c<8;++c) acc[c]=b1[c];
        #pragma unroll
        for (int blk=0; blk<12; ++blk) {
            float4 tv[4];
            #pragma unroll
            for (int u=0;u<4;++u) tv[u]=rowp[blk*4+u];
            #pragma unroll
            for (int c=0;c<8;++c) {
                const float* wrow = W1 + c*DIMD + blk*16;
                #pragma unroll
                for (int u=0;u<4;++u)
                    acc[c] += tv[u].x*wrow[u*4+0]+tv[u].y*wrow[u*4+1]
                            + tv[u].z*wrow[u*4+2]+tv[u].w*wrow[u*4+3];
            }
        }
        int h=tid/14, w=tid-h*14;
        float* tp = TS + (h+1)*16 + (w+1);
        #pragma unroll
        for (int c=0;c<8;++c) tp[c*256]=acc[c];
    } else if (tid >= 208) {
        ((float4*)outb)[tid-208] = ((const float4*)xb)[tid-208];
    }
    __syncthreads();
    if (tid < 196) {
        int h=tid/14, w=tid-h*14;
        const float* tp = TS + (h+1)*16 + (w+1);
        float zv[8];
        #pragma unroll
        for (int c=0;c<8;++c) zv[c]=conv1_b[c];
        #pragma unroll
        for (int i=0;i<8;++i) {
            float t0=tp[i*256], tu=tp[i*256-16], td=tp[i*256+16], tl=tp[i*256-1], tr=tp[i*256+1];
            #pragma unroll
            for (int c=0;c<8;++c) {
                const float* wp = WB2 + (c*8+i)*8;
                float4 wv = *(const float4*)wp;
                zv[c] += wv.x*t0 + wv.y*tu + wv.z*tl + wv.w*tr + wp[4]*td;
            }
        }
        float* pp = PS + (h+1)*16 + (w+1);
        #pragma unroll
        for (int c=0;c<8;++c) {
            float mu=0.f, ga=0.f;
            #pragma unroll
            for (int i=0;i<8;++i) {
                const float* wp = WB2 + (c*8+i)*8;
                mu += wp[5]*zv[i]; ga += wp[6]*zv[i];
            }
            float e = ga*(zv[c]-mu);
            pp[c*256] = __expf(-e*e);
        }
    }
    __syncthreads();
    if (tid < 196) {
        int h=tid/14, w=tid-h*14;
        const float* pb = PS + h*16 + w;
        #pragma unroll
        for (int c=0;c<8;++c) {
            const float* pr = pb + c*256;
            float s9 = pr[0]+pr[1]+pr[2]+pr[16]+pr[17]+pr[18]+pr[32]+pr[33]+pr[34];
            ZH[c*196+tid] = s9*(1.f/9.f);
        }
    }
    __syncthreads();
    if (tid < 192) {
        const int d4 = tid % 48, g = tid / 48;
        float hwf[32];
        const float4* hwp = (const float4*)(hist_w + d4*32);
        #pragma unroll
        for (int u=0;u<8;++u) {
            float4 v = hwp[u];
            hwf[u*4+0]=v.x; hwf[u*4+1]=v.y; hwf[u*4+2]=v.z; hwf[u*4+3]=v.w;
        }
        const float4 hb = *(const float4*)(hist_b + d4*4);
        float4* outy = (float4*)(outb + DIMD);
        for (int n2=g; n2<196; n2+=4) {
            const float4 z0 = *(const float4*)(ZH + n2*8);
            const float4 z1 = *(const float4*)(ZH + n2*8 + 4);
            float4 a = hb;
            a.x += z0.x*hwf[0] +z0.y*hwf[1] +z0.z*hwf[2] +z0.w*hwf[3]
                 + z1.x*hwf[4] +z1.y*hwf[5] +z1.z*hwf[6] +z1.w*hwf[7];
            a.y += z0.x*hwf[8] +z0.y*hwf[9] +z0.z*hwf[10]+z0.w*hwf[11]
                 + z1.x*hwf[12]+z1.y*hwf[13]+z1.z*hwf[14]+z1.w*hwf[15];
            a.z += z0.x*hwf[16]+z0.y*hwf[17]+z0.z*hwf[18]+z0.w*hwf[19]
                 + z1.x*hwf[20]+z1.y*hwf[21]+z1.z*hwf[22]+z1.w*hwf[23];
            a.w += z0.x*hwf[24]+z0.y*hwf[25]+z0.z*hwf[26]+z0.w*hwf[27]
                 + z1.x*hwf[28]+z1.y*hwf[29]+z1.z*hwf[30]+z1.w*hwf[31];
            outy[n2*48+d4] = a;
        }
    }
}

extern "C" void kernel_launch(void* const* d_in, const int* in_sizes, int n_in,
                              void* d_out, int out_size, void* d_ws, size_t ws_size,
                              hipStream_t stream)
{
    const float* x       = (const float*)d_in[0];
    const float* W1      = (const float*)d_in[1];
    const float* b1      = (const float*)d_in[2];
    const float* conv1_w = (const float*)d_in[3];
    const float* conv1_b = (const float*)d_in[4];
    const float* cdc_w   = (const float*)d_in[5];
    const float* wc1     = (const float*)d_in[6];
    const float* wc2     = (const float*)d_in[7];
    const float* hist_w  = (const float*)d_in[8];
    const float* hist_b  = (const float*)d_in[9];
    float* out = (float*)d_out;

    const size_t need = (size_t)2048 * 196 * 8 * sizeof(float);   // 12.85 MB
    if (ws_size >= need) {
        float* tbuf = (float*)d_ws;
        k1_tproj<<<1568, 256, 0, stream>>>(x, W1, b1, tbuf);
        k3_tail<<<2048, 256, 0, stream>>>(x, tbuf, conv1_w, conv1_b, cdc_w,
                                          wc1, wc2, hist_w, hist_b, out);
    } else {
        sadapter_fused<<<2048, 256, 0, stream>>>(
            x, W1, b1, conv1_w, conv1_b, cdc_w, wc1, wc2, hist_w, hist_b, out);
    }
}

// Round 8
// 155.433 us; speedup vs baseline: 3.2363x; 3.2363x over previous
//
#include <hip/hip_runtime.h>

// SAdapter v8: single fused kernel, one block per image (B=2048), 256 threads.
// Lessons applied: (v5/v7) no per-thread arrays >8 floats, no tight min-wave
// launch bounds -> no spills. (v4) no per-thread-row scatter stores. Phase D:
// thread = output dim d, 8 weights in 2 float4 regs, ZH via broadcast b128
// LDS reads, b32 coalesced full-line stores.
// LDS 18432 B; phases: 0 -> A -> BC -> C2 -> D (4 barriers).

#define DIMD 192

__launch_bounds__(256)
__global__ void sadapter_kernel(
    const float* __restrict__ x,
    const float* __restrict__ W1,
    const float* __restrict__ b1,
    const float* __restrict__ conv1_w,
    const float* __restrict__ conv1_b,
    const float* __restrict__ cdc_w,
    const float* __restrict__ wc1,
    const float* __restrict__ wc2,
    const float* __restrict__ hist_w,
    const float* __restrict__ hist_b,
    float* __restrict__ out)
{
    __shared__ float smem[4608];   // 18432 B
    float* TS  = smem;             // [8][16][16] padded t (border 0); dead after BC
    float* ZH  = smem;             // [1568] flat z_hist (c*196+hw), overlays TS
    float* PS  = smem + 2048;      // [8][16][16] padded P (border 1)
    float* WB2 = smem + 4096;      // [64][8] packed small weights

    const int tid = threadIdx.x;
    const float* xb   = x   + (size_t)blockIdx.x * (197 * DIMD);
    float*       outb = out + (size_t)blockIdx.x * (197 * DIMD);

    // ---- Phase 0: init borders, pack weights ----
    {
        float4 z4 = make_float4(0.f, 0.f, 0.f, 0.f);
        float4 o4 = make_float4(1.f, 1.f, 1.f, 1.f);
        ((float4*)TS)[tid]       = z4;
        ((float4*)TS)[tid + 256] = z4;
        ((float4*)PS)[tid]       = o4;
        ((float4*)PS)[tid + 256] = o4;
    }
    if (tid < 64) {
        const float* c5 = cdc_w + tid * 5;                 // cdc_w (8,8,1,5), tid=o*8+i
        float k0 = c5[0], k1 = c5[1], k2 = c5[2], k3 = c5[3], k4 = c5[4];
        float kd = k0 + k1 + k2 + k3 + k4;
        float* wp = WB2 + tid * 8;
        wp[0] = conv1_w[tid] + k2 - 0.7f * kd;  // center: 1x1 + cdc-center - theta*diff
        wp[1] = k0; wp[2] = k1; wp[3] = k3; wp[4] = k4;    // up,left,right,down
        wp[5] = wc1[tid];
        wp[6] = wc2[tid];
        wp[7] = 0.f;
    }
    __syncthreads();

    // ---- Phase A: t[n,c] = tok[n,:] @ W1[c,:] + b1[c] (per-token row GEMM) ----
    if (tid < 196) {
        const float4* rowp = (const float4*)(xb + DIMD + tid * DIMD);
        float acc[8];
        #pragma unroll
        for (int c = 0; c < 8; ++c) acc[c] = b1[c];        // uniform -> s_load
        #pragma unroll
        for (int blk = 0; blk < 6; ++blk) {                // 6 batches of 32 d
            float4 tv[8];
            #pragma unroll
            for (int u = 0; u < 8; ++u) tv[u] = rowp[blk * 8 + u];
            #pragma unroll
            for (int c = 0; c < 8; ++c) {
                const float* wrow = W1 + c * DIMD + blk * 32;  // contiguous, uniform
                #pragma unroll
                for (int u = 0; u < 8; ++u) {
                    acc[c] += tv[u].x * wrow[u * 4 + 0] + tv[u].y * wrow[u * 4 + 1]
                            + tv[u].z * wrow[u * 4 + 2] + tv[u].w * wrow[u * 4 + 3];
                }
            }
        }
        int h = tid / 14, w = tid - h * 14;
        float* tp = TS + (h + 1) * 16 + (w + 1);
        #pragma unroll
        for (int c = 0; c < 8; ++c) tp[c * 256] = acc[c];
    } else if (tid >= 208) {
        ((float4*)outb)[tid - 208] = ((const float4*)xb)[tid - 208];  // class token
    }
    __syncthreads();

    // ---- Phase BC: z_star in regs -> mu/gamma -> P = exp(-(g*(z-mu))^2) ----
    if (tid < 196) {
        int h = tid / 14, w = tid - h * 14;
        const float* tp = TS + (h + 1) * 16 + (w + 1);
        float zv[8];
        #pragma unroll
        for (int c = 0; c < 8; ++c) zv[c] = conv1_b[c];    // uniform -> s_load
        #pragma unroll
        for (int i = 0; i < 8; ++i) {
            float t0 = tp[i * 256];
            float tu = tp[i * 256 - 16];
            float td = tp[i * 256 + 16];
            float tl = tp[i * 256 - 1];
            float tr = tp[i * 256 + 1];
            #pragma unroll
            for (int c = 0; c < 8; ++c) {
                const float* wp = WB2 + (c * 8 + i) * 8;   // broadcast b128 + b32
                float4 wv = *(const float4*)wp;
                float wd = wp[4];
                zv[c] += wv.x * t0 + wv.y * tu + wv.z * tl + wv.w * tr + wd * td;
            }
        }
        float* pp = PS + (h + 1) * 16 + (w + 1);
        #pragma unroll
        for (int c = 0; c < 8; ++c) {
            float mu = 0.f, ga = 0.f;
            #pragma unroll
            for (int i = 0; i < 8; ++i) {
                const float* wp = WB2 + (c * 8 + i) * 8;
                mu += wp[5] * zv[i];
                ga += wp[6] * zv[i];
            }
            float e = ga * (zv[c] - mu);
            pp[c * 256] = __expf(-e * e);
        }
    }
    __syncthreads();

    // ---- Phase C2: z_hist = 3x3 box sum / 9, flat (c*196+hw) into ZH (over TS) ----
    if (tid < 196) {
        int h = tid / 14, w = tid - h * 14;
        const float* pb = PS + h * 16 + w;    // top-left of 3x3 window (padded coords)
        #pragma unroll
        for (int c = 0; c < 8; ++c) {
            const float* pr = pb + c * 256;
            float s9 = pr[0]  + pr[1]  + pr[2]
                     + pr[16] + pr[17] + pr[18]
                     + pr[32] + pr[33] + pr[34];
            ZH[c * 196 + tid] = s9 * (1.f / 9.f);
        }
    }
    __syncthreads();

    // ---- Phase D: thread = output dim d; 8 weights in regs; ZH broadcast reads;
    //      b32 coalesced stores (lane = d -> full 256B lines per wave) ----
    if (tid < DIMD) {
        const int d = tid;
        const float4 h0 = *(const float4*)(hist_w + d * 8);      // hist_w (192,8) row
        const float4 h1 = *(const float4*)(hist_w + d * 8 + 4);
        const float  hb = hist_b[d];
        float* oy = outb + DIMD;
        #pragma unroll 4
        for (int n2 = 0; n2 < 196; ++n2) {
            const float4 z0 = *(const float4*)(ZH + n2 * 8);     // broadcast b128
            const float4 z1 = *(const float4*)(ZH + n2 * 8 + 4); // broadcast b128
            float a = hb
                    + z0.x * h0.x + z0.y * h0.y + z0.z * h0.z + z0.w * h0.w
                    + z1.x * h1.x + z1.y * h1.y + z1.z * h1.z + z1.w * h1.w;
            oy[n2 * DIMD + d] = a;
        }
    }
}

extern "C" void kernel_launch(void* const* d_in, const int* in_sizes, int n_in,
                              void* d_out, int out_size, void* d_ws, size_t ws_size,
                              hipStream_t stream)
{
    const float* x       = (const float*)d_in[0];
    const float* W1      = (const float*)d_in[1];
    const float* b1      = (const float*)d_in[2];
    const float* conv1_w = (const float*)d_in[3];
    const float* conv1_b = (const float*)d_in[4];
    const float* cdc_w   = (const float*)d_in[5];
    const float* wc1     = (const float*)d_in[6];
    const float* wc2     = (const float*)d_in[7];
    const float* hist_w  = (const float*)d_in[8];
    const float* hist_b  = (const float*)d_in[9];
    float* out = (float*)d_out;

    sadapter_kernel<<<2048, 256, 0, stream>>>(
        x, W1, b1, conv1_w, conv1_b, cdc_w, wc1, wc2, hist_w, hist_b, out);
}

// Round 9
// 152.828 us; speedup vs baseline: 3.2915x; 1.0170x over previous
//
#include <hip/hip_runtime.h>

// SAdapter v9: single fused kernel, one block per image (B=2048), 256 threads.
// v8 + phase-D restructure: 4-wave row partition (wave w -> rows 49w..49w+48),
// each lane owns 3 output dims (l, l+64, l+128). LDS broadcast reads drop 3x
// (1176 -> 392 b128/block); all 256 threads active; stores stay coalesced.
// No tight launch bounds, no big per-thread arrays (v5/v7 spill lessons).

#define DIMD 192

__launch_bounds__(256)
__global__ void sadapter_kernel(
    const float* __restrict__ x,
    const float* __restrict__ W1,
    const float* __restrict__ b1,
    const float* __restrict__ conv1_w,
    const float* __restrict__ conv1_b,
    const float* __restrict__ cdc_w,
    const float* __restrict__ wc1,
    const float* __restrict__ wc2,
    const float* __restrict__ hist_w,
    const float* __restrict__ hist_b,
    float* __restrict__ out)
{
    __shared__ float smem[4608];   // 18432 B
    float* TS  = smem;             // [8][16][16] padded t (border 0); dead after BC
    float* ZH  = smem;             // [1568] flat z_hist (c*196+hw), overlays TS
    float* PS  = smem + 2048;      // [8][16][16] padded P (border 1)
    float* WB2 = smem + 4096;      // [64][8] packed small weights

    const int tid = threadIdx.x;
    const float* xb   = x   + (size_t)blockIdx.x * (197 * DIMD);
    float*       outb = out + (size_t)blockIdx.x * (197 * DIMD);

    // ---- Phase 0: init borders, pack weights ----
    {
        float4 z4 = make_float4(0.f, 0.f, 0.f, 0.f);
        float4 o4 = make_float4(1.f, 1.f, 1.f, 1.f);
        ((float4*)TS)[tid]       = z4;
        ((float4*)TS)[tid + 256] = z4;
        ((float4*)PS)[tid]       = o4;
        ((float4*)PS)[tid + 256] = o4;
    }
    if (tid < 64) {
        const float* c5 = cdc_w + tid * 5;                 // cdc_w (8,8,1,5), tid=o*8+i
        float k0 = c5[0], k1 = c5[1], k2 = c5[2], k3 = c5[3], k4 = c5[4];
        float kd = k0 + k1 + k2 + k3 + k4;
        float* wp = WB2 + tid * 8;
        wp[0] = conv1_w[tid] + k2 - 0.7f * kd;  // center: 1x1 + cdc-center - theta*diff
        wp[1] = k0; wp[2] = k1; wp[3] = k3; wp[4] = k4;    // up,left,right,down
        wp[5] = wc1[tid];
        wp[6] = wc2[tid];
        wp[7] = 0.f;
    }
    __syncthreads();

    // ---- Phase A: t[n,c] = tok[n,:] @ W1[c,:] + b1[c] (per-token row GEMM) ----
    if (tid < 196) {
        const float4* rowp = (const float4*)(xb + DIMD + tid * DIMD);
        float acc[8];
        #pragma unroll
        for (int c = 0; c < 8; ++c) acc[c] = b1[c];        // uniform -> s_load
        #pragma unroll
        for (int blk = 0; blk < 6; ++blk) {                // 6 batches of 32 d
            float4 tv[8];
            #pragma unroll
            for (int u = 0; u < 8; ++u) tv[u] = rowp[blk * 8 + u];
            #pragma unroll
            for (int c = 0; c < 8; ++c) {
                const float* wrow = W1 + c * DIMD + blk * 32;  // contiguous, uniform
                #pragma unroll
                for (int u = 0; u < 8; ++u) {
                    acc[c] += tv[u].x * wrow[u * 4 + 0] + tv[u].y * wrow[u * 4 + 1]
                            + tv[u].z * wrow[u * 4 + 2] + tv[u].w * wrow[u * 4 + 3];
                }
            }
        }
        int h = tid / 14, w = tid - h * 14;
        float* tp = TS + (h + 1) * 16 + (w + 1);
        #pragma unroll
        for (int c = 0; c < 8; ++c) tp[c * 256] = acc[c];
    } else if (tid >= 208) {
        ((float4*)outb)[tid - 208] = ((const float4*)xb)[tid - 208];  // class token
    }
    __syncthreads();

    // ---- Phase BC: z_star in regs -> mu/gamma -> P = exp(-(g*(z-mu))^2) ----
    if (tid < 196) {
        int h = tid / 14, w = tid - h * 14;
        const float* tp = TS + (h + 1) * 16 + (w + 1);
        float zv[8];
        #pragma unroll
        for (int c = 0; c < 8; ++c) zv[c] = conv1_b[c];    // uniform -> s_load
        #pragma unroll
        for (int i = 0; i < 8; ++i) {
            float t0 = tp[i * 256];
            float tu = tp[i * 256 - 16];
            float td = tp[i * 256 + 16];
            float tl = tp[i * 256 - 1];
            float tr = tp[i * 256 + 1];
            #pragma unroll
            for (int c = 0; c < 8; ++c) {
                const float* wp = WB2 + (c * 8 + i) * 8;   // broadcast b128 + b32
                float4 wv = *(const float4*)wp;
                float wd = wp[4];
                zv[c] += wv.x * t0 + wv.y * tu + wv.z * tl + wv.w * tr + wd * td;
            }
        }
        float* pp = PS + (h + 1) * 16 + (w + 1);
        #pragma unroll
        for (int c = 0; c < 8; ++c) {
            float mu = 0.f, ga = 0.f;
            #pragma unroll
            for (int i = 0; i < 8; ++i) {
                const float* wp = WB2 + (c * 8 + i) * 8;
                mu += wp[5] * zv[i];
                ga += wp[6] * zv[i];
            }
            float e = ga * (zv[c] - mu);
            pp[c * 256] = __expf(-e * e);
        }
    }
    __syncthreads();

    // ---- Phase D weights: issue global loads now; latency hides under C2 ----
    const int l  = tid & 63;          // lane
    const int wv = tid >> 6;          // wave 0..3
    const float4 ha0 = *(const float4*)(hist_w + l * 8);
    const float4 ha1 = *(const float4*)(hist_w + l * 8 + 4);
    const float4 hb0 = *(const float4*)(hist_w + (l + 64) * 8);
    const float4 hb1 = *(const float4*)(hist_w + (l + 64) * 8 + 4);
    const float4 hc0 = *(const float4*)(hist_w + (l + 128) * 8);
    const float4 hc1 = *(const float4*)(hist_w + (l + 128) * 8 + 4);
    const float  ba  = hist_b[l];
    const float  bb  = hist_b[l + 64];
    const float  bc  = hist_b[l + 128];

    // ---- Phase C2: z_hist = 3x3 box sum / 9, flat (c*196+hw) into ZH (over TS) ----
    if (tid < 196) {
        int h = tid / 14, w = tid - h * 14;
        const float* pb = PS + h * 16 + w;    // top-left of 3x3 window (padded coords)
        #pragma unroll
        for (int c = 0; c < 8; ++c) {
            const float* pr = pb + c * 256;
            float s9 = pr[0]  + pr[1]  + pr[2]
                     + pr[16] + pr[17] + pr[18]
                     + pr[32] + pr[33] + pr[34];
            ZH[c * 196 + tid] = s9 * (1.f / 9.f);
        }
    }
    __syncthreads();

    // ---- Phase D: wave wv -> rows 49wv..49wv+48; lane l -> dims l, l+64, l+128.
    //      2 broadcast b128 LDS reads per row per wave; coalesced 256B stores. ----
    {
        float* oy = outb + DIMD;
        const int n2beg = wv * 49;
        #pragma unroll 2
        for (int k = 0; k < 49; ++k) {
            const int n2 = n2beg + k;
            const float4 z0 = *(const float4*)(ZH + n2 * 8);     // broadcast b128
            const float4 z1 = *(const float4*)(ZH + n2 * 8 + 4); // broadcast b128
            float a0 = ba
                     + z0.x * ha0.x + z0.y * ha0.y + z0.z * ha0.z + z0.w * ha0.w
                     + z1.x * ha1.x + z1.y * ha1.y + z1.z * ha1.z + z1.w * ha1.w;
            float a1 = bb
                     + z0.x * hb0.x + z0.y * hb0.y + z0.z * hb0.z + z0.w * hb0.w
                     + z1.x * hb1.x + z1.y * hb1.y + z1.z * hb1.z + z1.w * hb1.w;
            float a2 = bc
                     + z0.x * hc0.x + z0.y * hc0.y + z0.z * hc0.z + z0.w * hc0.w
                     + z1.x * hc1.x + z1.y * hc1.y + z1.z * hc1.z + z1.w * hc1.w;
            float* orow = oy + n2 * DIMD;
            orow[l]       = a0;
            orow[l + 64]  = a1;
            orow[l + 128] = a2;
        }
    }
}

extern "C" void kernel_launch(void* const* d_in, const int* in_sizes, int n_in,
                              void* d_out, int out_size, void* d_ws, size_t ws_size,
                              hipStream_t stream)
{
    const float* x       = (const float*)d_in[0];
    const float* W1      = (const float*)d_in[1];
    const float* b1      = (const float*)d_in[2];
    const float* conv1_w = (const float*)d_in[3];
    const float* conv1_b = (const float*)d_in[4];
    const float* cdc_w   = (const float*)d_in[5];
    const float* wc1     = (const float*)d_in[6];
    const float* wc2     = (const float*)d_in[7];
    const float* hist_w  = (const float*)d_in[8];
    const float* hist_b  = (const float*)d_in[9];
    float* out = (float*)d_out;

    sadapter_kernel<<<2048, 256, 0, stream>>>(
        x, W1, b1, conv1_w, conv1_b, cdc_w, wc1, wc2, hist_w, hist_b, out);
}